// Round 1
// baseline (495.262 us; speedup 1.0000x reference)
//
#include <hip/hip_runtime.h>

#define NTOK 65536
#define DIM 256
#define KC 1024

#define BM 128
#define BN 128
#define BD 32
#define LP 36  // padded LDS row stride (floats): 36*4B = 144B, 16B-aligned, stride % 32 == 4

// ---------------- ||e_k||^2 ----------------
__global__ __launch_bounds__(256) void vq_esq(const float* __restrict__ e,
                                              float* __restrict__ esq) {
  const int wave = threadIdx.x >> 6;
  const int lane = threadIdx.x & 63;
  const int code = blockIdx.x * 4 + wave;
  const float4 v = *reinterpret_cast<const float4*>(&e[code * DIM + lane * 4]);
  float s = v.x * v.x + v.y * v.y + v.z * v.z + v.w * v.w;
#pragma unroll
  for (int o = 32; o > 0; o >>= 1) s += __shfl_down(s, o, 64);
  if (lane == 0) esq[code] = s;
}

// ---------------- distance GEMM + argmin ----------------
__global__ __launch_bounds__(256) void vq_argmin(
    const float* __restrict__ x, const float* __restrict__ e,
    const float* __restrict__ esq, int* __restrict__ outIdx,
    float* __restrict__ outIdxF, int* __restrict__ hist) {
  __shared__ float xs[BM][LP];
  __shared__ float es[BN][LP];
  __shared__ float redv[BM][17];
  __shared__ int   redi[BM][17];

  const int tid = threadIdx.x;
  const int tx = tid & 15;        // code group
  const int ty = tid >> 4;        // token group
  const int tokBase = blockIdx.x * BM;

  float bestv[8];
  int   besti[8];
#pragma unroll
  for (int i = 0; i < 8; ++i) { bestv[i] = 3.4e38f; besti[i] = 0; }

  for (int ct = 0; ct < KC / BN; ++ct) {
    float acc[8][8];
#pragma unroll
    for (int i = 0; i < 8; ++i)
#pragma unroll
      for (int j = 0; j < 8; ++j) acc[i][j] = 0.f;

    for (int dt = 0; dt < DIM / BD; ++dt) {
      __syncthreads();  // previous tile's readers done
      const int db = dt * BD;
      // stage x-tile [128][32] and e-tile [128][32]: 1024 float4 slots each
#pragma unroll
      for (int p = 0; p < 4; ++p) {
        const int s = tid + p * 256;
        const int row = s >> 3;
        const int d4 = (s & 7) * 4;
        const float4 xv =
            *reinterpret_cast<const float4*>(&x[(tokBase + row) * DIM + db + d4]);
        *reinterpret_cast<float4*>(&xs[row][d4]) = xv;
        const float4 ev =
            *reinterpret_cast<const float4*>(&e[(ct * BN + row) * DIM + db + d4]);
        *reinterpret_cast<float4*>(&es[row][d4]) = ev;
      }
      __syncthreads();

#pragma unroll
      for (int dd = 0; dd < BD; dd += 4) {
        float4 xa[8], eb[8];
#pragma unroll
        for (int i = 0; i < 8; ++i)
          xa[i] = *reinterpret_cast<const float4*>(&xs[i * 16 + ty][dd]);
#pragma unroll
        for (int j = 0; j < 8; ++j)
          eb[j] = *reinterpret_cast<const float4*>(&es[j * 16 + tx][dd]);
#pragma unroll
        for (int i = 0; i < 8; ++i)
#pragma unroll
          for (int j = 0; j < 8; ++j) {
            acc[i][j] = fmaf(xa[i].x, eb[j].x, acc[i][j]);
            acc[i][j] = fmaf(xa[i].y, eb[j].y, acc[i][j]);
            acc[i][j] = fmaf(xa[i].z, eb[j].z, acc[i][j]);
            acc[i][j] = fmaf(xa[i].w, eb[j].w, acc[i][j]);
          }
      }
    }

    // distances for this code tile; update running argmin.
    // within-thread codes ascend (j asc, ct asc) -> strict < keeps first min.
#pragma unroll
    for (int j = 0; j < 8; ++j) {
      const int code = ct * BN + j * 16 + tx;
      const float sq = esq[code];
#pragma unroll
      for (int i = 0; i < 8; ++i) {
        const float d = fmaf(-2.f, acc[i][j], sq);
        if (d < bestv[i]) { bestv[i] = d; besti[i] = code; }
      }
    }
  }

  // cross-thread (tx) reduction per token, lower-index tiebreak
#pragma unroll
  for (int i = 0; i < 8; ++i) {
    redv[i * 16 + ty][tx] = bestv[i];
    redi[i * 16 + ty][tx] = besti[i];
  }
  __syncthreads();
  if (tid < BM) {
    float bv = redv[tid][0];
    int   bi = redi[tid][0];
#pragma unroll
    for (int t = 1; t < 16; ++t) {
      const float v = redv[tid][t];
      const int  id = redi[tid][t];
      if (v < bv || (v == bv && id < bi)) { bv = v; bi = id; }
    }
    const int g = tokBase + tid;
    outIdx[g] = bi;
    outIdxF[g] = (float)bi;
    atomicAdd(&hist[bi], 1);
  }
}

// ---------------- gather + loss partials ----------------
__global__ __launch_bounds__(256) void vq_gather(
    const float* __restrict__ x, const float* __restrict__ e,
    const int* __restrict__ idx, float* __restrict__ outQ,
    float* __restrict__ partial) {
  const int tid = threadIdx.x;
  const int gtid = blockIdx.x * 256 + tid;
  float sum = 0.f;
#pragma unroll
  for (int p = 0; p < 8; ++p) {
    const int s = gtid + p * 524288;       // NTOK*64 float4 slots total
    const int tok = s >> 6;
    const int d4 = (s & 63) * 4;
    const int id = idx[tok];
    const float4 q = *reinterpret_cast<const float4*>(&e[id * DIM + d4]);
    const float4 xv = *reinterpret_cast<const float4*>(&x[tok * DIM + d4]);
    *reinterpret_cast<float4*>(&outQ[tok * DIM + d4]) = q;
    const float d0 = q.x - xv.x, d1 = q.y - xv.y, d2 = q.z - xv.z, d3 = q.w - xv.w;
    sum += d0 * d0 + d1 * d1 + d2 * d2 + d3 * d3;
  }
#pragma unroll
  for (int o = 32; o > 0; o >>= 1) sum += __shfl_down(sum, o, 64);
  __shared__ float wsum[4];
  const int lane = tid & 63, w = tid >> 6;
  if (lane == 0) wsum[w] = sum;
  __syncthreads();
  if (tid == 0) partial[blockIdx.x] = wsum[0] + wsum[1] + wsum[2] + wsum[3];
}

// ---------------- final scalars ----------------
__global__ __launch_bounds__(1024) void vq_final(
    const int* __restrict__ hist, const float* __restrict__ partial,
    float* __restrict__ outLoss, float* __restrict__ outPerp) {
  const int tid = threadIdx.x;
  float ls = partial[tid] + partial[tid + 1024];
  const float p = (float)hist[tid] * (1.f / 65536.f);
  float ent = p * logf(p + 1e-10f);
#pragma unroll
  for (int o = 32; o > 0; o >>= 1) {
    ls += __shfl_down(ls, o, 64);
    ent += __shfl_down(ent, o, 64);
  }
  __shared__ float lbuf[16], ebuf[16];
  const int lane = tid & 63, w = tid >> 6;
  if (lane == 0) { lbuf[w] = ls; ebuf[w] = ent; }
  __syncthreads();
  if (tid == 0) {
    float L = 0.f, E = 0.f;
    for (int i = 0; i < 16; ++i) { L += lbuf[i]; E += ebuf[i]; }
    *outLoss = 0.25f * (L / 16777216.f);
    *outPerp = expf(-E);
  }
}

extern "C" void kernel_launch(void* const* d_in, const int* in_sizes, int n_in,
                              void* d_out, int out_size, void* d_ws, size_t ws_size,
                              hipStream_t stream) {
  const float* x = (const float*)d_in[0];   // [65536, 256]
  const float* e = (const float*)d_in[1];   // [1024, 256]
  float* out = (float*)d_out;
  float* outQ = out;                        // 16777216
  float* outLoss = out + 16777216;
  float* outPerp = out + 16777217;
  float* outIdxF = out + 16777218;          // 65536

  char* ws = (char*)d_ws;
  int*   idx     = (int*)ws;                  // 262144 B
  int*   hist    = (int*)(ws + 262144);       // 4096 B
  float* partial = (float*)(ws + 266240);     // 8192 B (2048 floats)
  float* esq     = (float*)(ws + 274432);     // 4096 B

  hipMemsetAsync(hist, 0, KC * sizeof(int), stream);
  vq_esq<<<KC / 4, 256, 0, stream>>>(e, esq);
  vq_argmin<<<NTOK / BM, 256, 0, stream>>>(x, e, esq, idx, outIdxF, hist);
  vq_gather<<<2048, 256, 0, stream>>>(x, e, idx, outQ, partial);
  vq_final<<<1, 1024, 0, stream>>>(hist, partial, outLoss, outPerp);
}

// Round 2
// 256.883 us; speedup vs baseline: 1.9280x; 1.9280x over previous
//
#include <hip/hip_runtime.h>

#define NTOK 65536
#define DIM 256
#define KC 1024
#define EPS 0.02f

typedef __attribute__((ext_vector_type(8))) short bf16x8;
typedef __attribute__((ext_vector_type(4))) float f32x4;

static __device__ __forceinline__ unsigned short bf16_rn(float f) {
  unsigned u = __float_as_uint(f);
  u += 0x7FFFu + ((u >> 16) & 1u);
  return (unsigned short)(u >> 16);
}
static __device__ __forceinline__ float bf16_tof(unsigned short h) {
  return __uint_as_float(((unsigned)h) << 16);
}
static __device__ __forceinline__ void gload16(const void* g, void* l) {
  __builtin_amdgcn_global_load_lds(
      (const __attribute__((address_space(1))) unsigned int*)g,
      (__attribute__((address_space(3))) unsigned int*)l, 16, 0, 0);
}

// ---------------- fp32 -> bf16 hi/lo split ----------------
__global__ __launch_bounds__(256) void vq_split(const float* __restrict__ in,
                                                unsigned short* __restrict__ hi,
                                                unsigned short* __restrict__ lo,
                                                int nvec4) {
  const int stride = gridDim.x * 256;
  for (int s = blockIdx.x * 256 + threadIdx.x; s < nvec4; s += stride) {
    const float4 v = ((const float4*)in)[s];
    ushort4 h, l;
    h.x = bf16_rn(v.x); l.x = bf16_rn(v.x - bf16_tof(h.x));
    h.y = bf16_rn(v.y); l.y = bf16_rn(v.y - bf16_tof(h.y));
    h.z = bf16_rn(v.z); l.z = bf16_rn(v.z - bf16_tof(h.z));
    h.w = bf16_rn(v.w); l.w = bf16_rn(v.w - bf16_tof(h.w));
    ((ushort4*)hi)[s] = h;
    ((ushort4*)lo)[s] = l;
  }
}

// ---------------- ||e_k||^2 (exact fp32) ----------------
__global__ __launch_bounds__(256) void vq_esq(const float* __restrict__ e,
                                              float* __restrict__ esq) {
  const int wave = threadIdx.x >> 6;
  const int lane = threadIdx.x & 63;
  const int code = blockIdx.x * 4 + wave;
  const float4 v = *reinterpret_cast<const float4*>(&e[code * DIM + lane * 4]);
  float s = v.x * v.x + v.y * v.y + v.z * v.z + v.w * v.w;
#pragma unroll
  for (int o = 32; o > 0; o >>= 1) s += __shfl_down(s, o, 64);
  if (lane == 0) esq[code] = s;
}

// ---------------- MFMA distance GEMM + argmin(+second) ----------------
__global__ __launch_bounds__(256, 2) void vq_mfma_argmin(
    const unsigned short* __restrict__ xh, const unsigned short* __restrict__ xl,
    const unsigned short* __restrict__ eh, const unsigned short* __restrict__ el,
    const float* __restrict__ esq,
    int* __restrict__ outIdx, float* __restrict__ outIdxF,
    int* __restrict__ fixCount, int* __restrict__ fixList) {
  __shared__ unsigned short xsh[128][64];
  __shared__ unsigned short xsl[128][64];
  __shared__ unsigned short esh[128][64];
  __shared__ unsigned short esl[128][64];
  __shared__ float redB[2][128];
  __shared__ float redS[2][128];
  __shared__ int   redI[2][128];

  const int tid = threadIdx.x;
  const int lane = tid & 63;
  const int w = tid >> 6;
  const int wr = w >> 1;   // token half (0/1)
  const int wc = w & 1;    // code half (0/1)
  const int tokBase = blockIdx.x * 128;
  const int col = lane & 15;
  const int rquad = lane >> 4;  // 0..3

  f32x4 acc[4][4];
  float best[4][4], second[4][4];
  int bidx[4][4];
#pragma unroll
  for (int mi = 0; mi < 4; ++mi)
#pragma unroll
    for (int r = 0; r < 4; ++r) {
      best[mi][r] = 3.4e38f; second[mi][r] = 3.4e38f; bidx[mi][r] = 0;
    }

  const int srow = lane >> 3;       // row within 8-row staging stripe
  const int scol = (lane & 7) * 8;  // ushort column

  for (int ct = 0; ct < 8; ++ct) {
#pragma unroll
    for (int mi = 0; mi < 4; ++mi)
#pragma unroll
      for (int nj = 0; nj < 4; ++nj) acc[mi][nj] = (f32x4){0.f, 0.f, 0.f, 0.f};

    for (int kt = 0; kt < 4; ++kt) {
      __syncthreads();  // previous tile consumed
      const int kOff = kt * 64;
#pragma unroll
      for (int q = 0; q < 4; ++q) {
        const int r0 = (w * 4 + q) * 8;
        const int xr = tokBase + r0 + srow;
        const int er = ct * 128 + r0 + srow;
        gload16(&xh[xr * DIM + kOff + scol], &xsh[r0][0]);
        gload16(&xl[xr * DIM + kOff + scol], &xsl[r0][0]);
        gload16(&eh[er * DIM + kOff + scol], &esh[r0][0]);
        gload16(&el[er * DIM + kOff + scol], &esl[r0][0]);
      }
      __syncthreads();  // drains vmcnt(0): tiles ready

#pragma unroll
      for (int ks = 0; ks < 2; ++ks) {
        const int kc = ks * 32 + rquad * 8;
        bf16x8 ah[4], al[4], bh[4], bl[4];
#pragma unroll
        for (int mi = 0; mi < 4; ++mi) {
          const int rr = wr * 64 + mi * 16 + col;
          ah[mi] = *(const bf16x8*)&xsh[rr][kc];
          al[mi] = *(const bf16x8*)&xsl[rr][kc];
        }
#pragma unroll
        for (int nj = 0; nj < 4; ++nj) {
          const int rr = wc * 64 + nj * 16 + col;
          bh[nj] = *(const bf16x8*)&esh[rr][kc];
          bl[nj] = *(const bf16x8*)&esl[rr][kc];
        }
#pragma unroll
        for (int mi = 0; mi < 4; ++mi)
#pragma unroll
          for (int nj = 0; nj < 4; ++nj) {
            acc[mi][nj] = __builtin_amdgcn_mfma_f32_16x16x32_bf16(ah[mi], bh[nj], acc[mi][nj], 0, 0, 0);
            acc[mi][nj] = __builtin_amdgcn_mfma_f32_16x16x32_bf16(ah[mi], bl[nj], acc[mi][nj], 0, 0, 0);
            acc[mi][nj] = __builtin_amdgcn_mfma_f32_16x16x32_bf16(al[mi], bh[nj], acc[mi][nj], 0, 0, 0);
          }
      }
    }

    // epilogue: distances for this 128-code chunk, update best/second.
    // per-lane candidate codes ascend over (ct, nj) -> strict < keeps first min.
#pragma unroll
    for (int nj = 0; nj < 4; ++nj) {
      const int code = ct * 128 + wc * 64 + nj * 16 + col;
      const float sq = esq[code];
#pragma unroll
      for (int mi = 0; mi < 4; ++mi)
#pragma unroll
        for (int r = 0; r < 4; ++r) {
          const float d = fmaf(-2.f, acc[mi][nj][r], sq);
          if (d < best[mi][r]) {
            second[mi][r] = best[mi][r];
            best[mi][r] = d;
            bidx[mi][r] = code;
          } else if (d < second[mi][r]) {
            second[mi][r] = d;
          }
        }
    }
  }

  // cross-lane reduce over the 16 lanes sharing rquad (xor masks 1,2,4,8)
#pragma unroll
  for (int mi = 0; mi < 4; ++mi)
#pragma unroll
    for (int r = 0; r < 4; ++r) {
      float b = best[mi][r], s2 = second[mi][r];
      int bi = bidx[mi][r];
#pragma unroll
      for (int m = 1; m <= 8; m <<= 1) {
        const float ob = __shfl_xor(b, m, 64);
        const float os = __shfl_xor(s2, m, 64);
        const int   oi = __shfl_xor(bi, m, 64);
        s2 = fminf(fminf(s2, os), fmaxf(b, ob));
        if (ob < b || (ob == b && oi < bi)) { b = ob; bi = oi; }
      }
      if (col == 0) {
        const int row = wr * 64 + mi * 16 + rquad * 4 + r;
        redB[wc][row] = b; redS[wc][row] = s2; redI[wc][row] = bi;
      }
    }
  __syncthreads();
  if (tid < 128) {
    const float b0 = redB[0][tid], b1 = redB[1][tid];
    const float s0 = redS[0][tid], s1 = redS[1][tid];
    const int i0 = redI[0][tid], i1 = redI[1][tid];
    const float s2 = fminf(fminf(s0, s1), fmaxf(b0, b1));
    float b; int bi;
    if (b1 < b0 || (b1 == b0 && i1 < i0)) { b = b1; bi = i1; } else { b = b0; bi = i0; }
    const int t = tokBase + tid;
    outIdx[t] = bi;
    outIdxF[t] = (float)bi;
    if (s2 - b < EPS) {
      const int p = atomicAdd(fixCount, 1);
      fixList[p] = t;
    }
  }
}

// ---------------- exact fp32 rescan for near-tie tokens ----------------
__global__ __launch_bounds__(256) void vq_fixup(
    const float* __restrict__ x, const float* __restrict__ e,
    const float* __restrict__ esq, const int* __restrict__ fixCount,
    const int* __restrict__ fixList, int* __restrict__ outIdx,
    float* __restrict__ outIdxF) {
  const int n = *fixCount;
  __shared__ float xrow[256];
  __shared__ float rv[4];
  __shared__ int ri[4];
  const int tid = threadIdx.x;
  for (int it = blockIdx.x; it < n; it += gridDim.x) {
    const int t = fixList[it];
    __syncthreads();
    if (tid < 64) ((float4*)xrow)[tid] = ((const float4*)&x[t * DIM])[tid];
    __syncthreads();
    float bv = 3.4e38f; int bi = 0;
    for (int c = tid; c < KC; c += 256) {
      float s = 0.f;
#pragma unroll
      for (int d = 0; d < DIM; d += 4) {
        const float4 ev = *(const float4*)&e[c * DIM + d];
        s = fmaf(xrow[d], ev.x, s);
        s = fmaf(xrow[d + 1], ev.y, s);
        s = fmaf(xrow[d + 2], ev.z, s);
        s = fmaf(xrow[d + 3], ev.w, s);
      }
      const float dist = fmaf(-2.f, s, esq[c]);
      if (dist < bv) { bv = dist; bi = c; }  // c ascends per thread
    }
#pragma unroll
    for (int m = 1; m <= 32; m <<= 1) {
      const float ob = __shfl_xor(bv, m, 64);
      const int oi = __shfl_xor(bi, m, 64);
      if (ob < bv || (ob == bv && oi < bi)) { bv = ob; bi = oi; }
    }
    const int lane = tid & 63, wv = tid >> 6;
    if (lane == 0) { rv[wv] = bv; ri[wv] = bi; }
    __syncthreads();
    if (tid == 0) {
      float fb = rv[0]; int fi = ri[0];
      for (int k = 1; k < 4; ++k)
        if (rv[k] < fb || (rv[k] == fb && ri[k] < fi)) { fb = rv[k]; fi = ri[k]; }
      outIdx[t] = fi;
      outIdxF[t] = (float)fi;
    }
  }
}

// ---------------- histogram ----------------
__global__ __launch_bounds__(256) void vq_hist(const int* __restrict__ idx,
                                               int* __restrict__ hist) {
  atomicAdd(&hist[idx[blockIdx.x * 256 + threadIdx.x]], 1);
}

// ---------------- gather + loss partials ----------------
__global__ __launch_bounds__(256) void vq_gather(
    const float* __restrict__ x, const float* __restrict__ e,
    const int* __restrict__ idx, float* __restrict__ outQ,
    float* __restrict__ partial) {
  const int tid = threadIdx.x;
  const int gtid = blockIdx.x * 256 + tid;
  float sum = 0.f;
#pragma unroll
  for (int p = 0; p < 8; ++p) {
    const int s = gtid + p * 524288;
    const int tok = s >> 6;
    const int d4 = (s & 63) * 4;
    const int id = idx[tok];
    const float4 q = *reinterpret_cast<const float4*>(&e[id * DIM + d4]);
    const float4 xv = *reinterpret_cast<const float4*>(&x[tok * DIM + d4]);
    *reinterpret_cast<float4*>(&outQ[tok * DIM + d4]) = q;
    const float d0 = q.x - xv.x, d1 = q.y - xv.y, d2 = q.z - xv.z, d3 = q.w - xv.w;
    sum += d0 * d0 + d1 * d1 + d2 * d2 + d3 * d3;
  }
#pragma unroll
  for (int o = 32; o > 0; o >>= 1) sum += __shfl_down(sum, o, 64);
  __shared__ float wsum[4];
  const int lane = tid & 63, wv = tid >> 6;
  if (lane == 0) wsum[wv] = sum;
  __syncthreads();
  if (tid == 0) partial[blockIdx.x] = wsum[0] + wsum[1] + wsum[2] + wsum[3];
}

// ---------------- final scalars ----------------
__global__ __launch_bounds__(1024) void vq_final(
    const int* __restrict__ hist, const float* __restrict__ partial,
    float* __restrict__ outLoss, float* __restrict__ outPerp) {
  const int tid = threadIdx.x;
  float ls = partial[tid] + partial[tid + 1024];
  const float p = (float)hist[tid] * (1.f / 65536.f);
  float ent = p * logf(p + 1e-10f);
#pragma unroll
  for (int o = 32; o > 0; o >>= 1) {
    ls += __shfl_down(ls, o, 64);
    ent += __shfl_down(ent, o, 64);
  }
  __shared__ float lbuf[16], ebuf[16];
  const int lane = tid & 63, wv = tid >> 6;
  if (lane == 0) { lbuf[wv] = ls; ebuf[wv] = ent; }
  __syncthreads();
  if (tid == 0) {
    float L = 0.f, E = 0.f;
    for (int i = 0; i < 16; ++i) { L += lbuf[i]; E += ebuf[i]; }
    *outLoss = 0.25f * (L / 16777216.f);
    *outPerp = expf(-E);
  }
}

extern "C" void kernel_launch(void* const* d_in, const int* in_sizes, int n_in,
                              void* d_out, int out_size, void* d_ws, size_t ws_size,
                              hipStream_t stream) {
  const float* x = (const float*)d_in[0];  // [65536, 256]
  const float* e = (const float*)d_in[1];  // [1024, 256]
  float* out = (float*)d_out;
  float* outQ = out;                 // 16777216 floats
  float* outLoss = out + 16777216;
  float* outPerp = out + 16777217;
  float* outIdxF = out + 16777218;   // 65536 floats

  // x bf16 splits live in d_out's quantized region (written last by vq_gather):
  // x_hi: bytes [0, 33554432), x_lo: bytes [33554432, 67108864) == 16777216 floats.
  unsigned short* x_hi = (unsigned short*)d_out;
  unsigned short* x_lo = (unsigned short*)((char*)d_out + 33554432);

  char* ws = (char*)d_ws;
  int*   idx      = (int*)ws;                    // 262144 B
  int*   hist     = (int*)(ws + 262144);         // 4096 B
  float* partial  = (float*)(ws + 266240);       // 8192 B
  float* esq      = (float*)(ws + 274432);       // 4096 B
  int*   fixCount = (int*)(ws + 278528);         // 16 B
  int*   fixList  = (int*)(ws + 282624);         // 262144 B
  unsigned short* e_hi = (unsigned short*)(ws + 544768);   // 524288 B
  unsigned short* e_lo = (unsigned short*)(ws + 1069056);  // 524288 B
  // total ws use: ~1.56 MB

  hipMemsetAsync(hist, 0, KC * sizeof(int), stream);
  hipMemsetAsync(fixCount, 0, sizeof(int), stream);
  vq_split<<<2048, 256, 0, stream>>>(x, x_hi, x_lo, NTOK * DIM / 4);
  vq_split<<<256, 256, 0, stream>>>(e, e_hi, e_lo, KC * DIM / 4);
  vq_esq<<<KC / 4, 256, 0, stream>>>(e, esq);
  vq_mfma_argmin<<<NTOK / 128, 256, 0, stream>>>(x_hi, x_lo, e_hi, e_lo, esq,
                                                 idx, outIdxF, fixCount, fixList);
  vq_fixup<<<256, 256, 0, stream>>>(x, e, esq, fixCount, fixList, idx, outIdxF);
  vq_hist<<<NTOK / 256, 256, 0, stream>>>(idx, hist);
  vq_gather<<<2048, 256, 0, stream>>>(x, e, idx, outQ, partial);
  vq_final<<<1, 1024, 0, stream>>>(hist, partial, outLoss, outPerp);
}